// Round 3
// baseline (2474.452 us; speedup 1.0000x reference)
//
#include <hip/hip_runtime.h>
#include <hip/hip_bf16.h>

#define S_ 8
#define B_ 32
#define T_ 512
#define I_ 256
#define H_ 512
#define O_ 32

typedef __attribute__((ext_vector_type(8))) short short8;
typedef __attribute__((ext_vector_type(4))) float float4_;

__device__ inline unsigned short f2bf(float f) {
    unsigned u = __float_as_uint(f);
    u = (u + 0x7fffu + ((u >> 16) & 1u)) >> 16;   // RNE
    return (unsigned short)u;
}

__device__ inline short8 load_cvt8(const float* p) {
    float4_ a = *reinterpret_cast<const float4_*>(p);
    float4_ b = *reinterpret_cast<const float4_*>(p + 4);
    short8 r;
    r[0] = (short)f2bf(a[0]); r[1] = (short)f2bf(a[1]);
    r[2] = (short)f2bf(a[2]); r[3] = (short)f2bf(a[3]);
    r[4] = (short)f2bf(b[0]); r[5] = (short)f2bf(b[1]);
    r[6] = (short)f2bf(b[2]); r[7] = (short)f2bf(b[3]);
    return r;
}

// Agent-coherent accesses: sc0 sc1 bypass non-coherent caches and hit the
// coherence point (LLC). Loads valid only after s_waitcnt vmcnt(0).
__device__ inline short8 load_h16_coherent(const unsigned short* p) {
    short8 v;
    asm volatile("global_load_dwordx4 %0, %1, off sc0 sc1"
                 : "=v"(v) : "v"(p) : "memory");
    return v;
}
__device__ inline unsigned load_u32_coherent(const unsigned* p) {
    unsigned v;
    asm volatile("global_load_dword %0, %1, off sc0 sc1"
                 : "=v"(v) : "v"(p) : "memory");
    return v;
}
__device__ inline void store_h2_coherent(unsigned short* p, unsigned v) {
    asm volatile("global_store_short %0, %1, off sc0 sc1"
                 :: "v"(p), "v"(v) : "memory");
}
__device__ inline void store_u32_coherent(unsigned* p, unsigned v) {
    asm volatile("global_store_dword %0, %1, off sc0 sc1"
                 :: "v"(p), "v"(v) : "memory");
}
__device__ inline void wait_vm0_fence() {
    asm volatile("s_waitcnt vmcnt(0)" ::: "memory");
    __builtin_amdgcn_sched_barrier(0);   // rule #18: nothing hoists above the wait
}

// ws layout (bytes):
//   [0, 524288)            : h bf16 double buffer [2][S][B][H]
//   [524288, 540672)       : hbar fp32 [S][H]
//   [540672, 542720)       : flags  uint [S][64]  (j*2+m), 256B per seq
//   [542720, 544768)       : done counters, uint per seq, 256B stride
#define WS_NEED 544768

__global__ __launch_bounds__(256, 1)
void zgru_persistent(const float* __restrict__ x, const int* __restrict__ lens,
                     const float* __restrict__ Wih, const float* __restrict__ Whh,
                     const float* __restrict__ bih, const float* __restrict__ bhh,
                     const float* __restrict__ Wout, const float* __restrict__ bout,
                     float* __restrict__ out,
                     unsigned short* __restrict__ hbuf, float* __restrict__ hbar,
                     unsigned* __restrict__ flags, unsigned* __restrict__ done_ctr)
{
    const int tid  = threadIdx.x;
    const int wg   = blockIdx.x;
    const int s    = wg & 7;         // sequence  (round-robin -> all 32 WGs of a seq on one XCD)
    const int j    = wg >> 3;        // hidden-col group: cols [16j, 16j+16)
    const int wid  = tid >> 6;
    const int lane = tid & 63;
    const int m    = wid >> 1;       // batch half (rows 16m..16m+15)
    const int kh   = wid & 1;        // K half
    const int lrow = lane & 15;      // A-row / B-col / C-col within tile
    const int lgrp = lane >> 4;      // k-group (A/B) or row-group (C)

    const int len = lens[s];

    // ---- persistent B fragments (weights, bf16), pinned in VGPRs --------
    short8 bhR[8], bhZ[8], bhN[8];   // W_hh, K half = 256 -> 8 chunks of 32
    short8 bxR[4], bxZ[4], bxN[4];   // W_ih, K half = 128 -> 4 chunks of 32
    {
        const int gr = 16 * j + lrow;
        #pragma unroll
        for (int kc = 0; kc < 8; ++kc) {
            const int k0 = 256 * kh + 32 * kc + 8 * lgrp;
            bhR[kc] = load_cvt8(Whh + (size_t)(gr          ) * H_ + k0);
            bhZ[kc] = load_cvt8(Whh + (size_t)(gr +     H_ ) * H_ + k0);
            bhN[kc] = load_cvt8(Whh + (size_t)(gr + 2 * H_ ) * H_ + k0);
        }
        #pragma unroll
        for (int kc = 0; kc < 4; ++kc) {
            const int k0 = 128 * kh + 32 * kc + 8 * lgrp;
            bxR[kc] = load_cvt8(Wih + (size_t)(gr          ) * I_ + k0);
            bxZ[kc] = load_cvt8(Wih + (size_t)(gr +     H_ ) * I_ + k0);
            bxN[kc] = load_cvt8(Wih + (size_t)(gr + 2 * H_ ) * I_ + k0);
        }
        #pragma unroll
        for (int kc = 0; kc < 8; ++kc)
            asm volatile("" : "+v"(bhR[kc]), "+v"(bhZ[kc]), "+v"(bhN[kc]));
        #pragma unroll
        for (int kc = 0; kc < 4; ++kc)
            asm volatile("" : "+v"(bxR[kc]), "+v"(bxZ[kc]), "+v"(bxN[kc]));
    }

    const int gcol   = 16 * j + lrow;            // this lane's hidden col (C layout)
    const float bsR  = bih[gcol] + bhh[gcol];
    const float bsZ  = bih[H_ + gcol] + bhh[H_ + gcol];
    const float biN  = bih[2 * H_ + gcol];
    const float bhN_ = bhh[2 * H_ + gcol];

    float h[4] = {0.f, 0.f, 0.f, 0.f};           // fp32 state, rows 16m+4*lgrp+i, col gcol

    __shared__ float4_ xch[2][2][4][64];         // [t&1][m][gate][lane] K-half exchange
    __shared__ unsigned last_flag;
    __shared__ float red[8][32];

    const size_t HBUF = (size_t)S_ * B_ * H_;    // elements per h buffer
    const int arow = 16 * m + lrow;              // A row (batch index)
    const unsigned* fl = flags + s * 64;         // this seq's 64 per-wave flags
    unsigned* myflag = flags + s * 64 + j * 2 + m;

    for (int t = 0; t < len; ++t) {
        // ---- recurrence-independent x part: load + 12 MFMAs, pre-barrier
        float4_ aR = {0,0,0,0}, aZ = {0,0,0,0}, aNX = {0,0,0,0};
        {
            const float* xb = x + (((size_t)s * B_ + arow) * T_ + t) * I_ + 128 * kh + 8 * lgrp;
            #pragma unroll
            for (int kc = 0; kc < 4; ++kc) {
                short8 ax = load_cvt8(xb + 32 * kc);
                aR  = __builtin_amdgcn_mfma_f32_16x16x32_bf16(ax, bxR[kc], aR, 0, 0, 0);
                aZ  = __builtin_amdgcn_mfma_f32_16x16x32_bf16(ax, bxZ[kc], aZ, 0, 0, 0);
                aNX = __builtin_amdgcn_mfma_f32_16x16x32_bf16(ax, bxN[kc], aNX, 0, 0, 0);
            }
        }

        if (t > 0) {   // contention-free barrier: every wave polls all 64 flags
            const unsigned tgt = (unsigned)t;
            for (;;) {
                unsigned fv = load_u32_coherent(fl + lane);
                asm volatile("s_waitcnt vmcnt(0)" ::: "memory");
                if (__ballot(fv >= tgt) == ~0ull) break;
            }
            __builtin_amdgcn_sched_barrier(0);
        }

        // ---- h A-fragments, agent-coherent (read LLC) -------------------
        const unsigned short* hr = hbuf + (size_t)(t & 1) * HBUF + (size_t)s * B_ * H_;
        short8 ah[8];
        #pragma unroll
        for (int kc = 0; kc < 8; ++kc) {
            const int k0 = 256 * kh + 32 * kc + 8 * lgrp;
            ah[kc] = load_h16_coherent(hr + (size_t)arow * H_ + k0);
        }
        wait_vm0_fence();

        float4_ aNH = {0,0,0,0};
        #pragma unroll
        for (int kc = 0; kc < 8; ++kc) {
            aR  = __builtin_amdgcn_mfma_f32_16x16x32_bf16(ah[kc], bhR[kc], aR, 0, 0, 0);
            aZ  = __builtin_amdgcn_mfma_f32_16x16x32_bf16(ah[kc], bhZ[kc], aZ, 0, 0, 0);
            aNH = __builtin_amdgcn_mfma_f32_16x16x32_bf16(ah[kc], bhN[kc], aNH, 0, 0, 0);
        }

        if (kh == 1) {  // publish K-half partials (double-buffered by t&1)
            xch[t & 1][m][0][lane] = aR;
            xch[t & 1][m][1][lane] = aZ;
            xch[t & 1][m][2][lane] = aNH;
            xch[t & 1][m][3][lane] = aNX;
        }
        __syncthreads();
        if (kh == 0) {  // merge, gates, state update, publish bf16 h + flag
            aR  += xch[t & 1][m][0][lane];
            aZ  += xch[t & 1][m][1][lane];
            aNH += xch[t & 1][m][2][lane];
            aNX += xch[t & 1][m][3][lane];
            unsigned short* hw = hbuf + (size_t)((t + 1) & 1) * HBUF + (size_t)s * B_ * H_;
            #pragma unroll
            for (int i = 0; i < 4; ++i) {
                const float pr = aR[i] + bsR;
                const float pz = aZ[i] + bsZ;
                const float r = 1.f / (1.f + __expf(-pr));
                const float z = 1.f / (1.f + __expf(-pz));
                const float pn = aNX[i] + biN + r * (aNH[i] + bhN_);
                const float e = __expf(-2.f * fabsf(pn));
                float n = (1.f - e) / (1.f + e);
                n = copysignf(n, pn);
                h[i] = z * (h[i] - n) + n;
                store_h2_coherent(hw + (size_t)(16 * m + 4 * lgrp + i) * H_ + gcol,
                                  (unsigned)f2bf(h[i]));
            }
            asm volatile("s_waitcnt vmcnt(0)" ::: "memory");  // h visible at LLC
            if (lane == 0)
                store_u32_coherent(myflag, (unsigned)(t + 1));
        }
        // no trailing __syncthreads: waves self-gate on the flag poll
    }

    // ---- hbar[s][col] = sum_b h ----------------------------------------
    float s4 = h[0] + h[1] + h[2] + h[3];
    s4 += __shfl_xor(s4, 16);
    s4 += __shfl_xor(s4, 32);
    if (kh == 0 && lgrp == 0)
        atomicAdd(&hbar[(size_t)s * H_ + gcol], s4);   // device-scope by default

    __syncthreads();   // drains the atomicAdd (vmcnt 0)
    if (tid == 0) {
        unsigned old = __hip_atomic_fetch_add(&done_ctr[s * 64], 1u, __ATOMIC_RELAXED, __HIP_MEMORY_SCOPE_AGENT);
        last_flag = (old == 31u) ? 1u : 0u;
    }
    __syncthreads();
    if (last_flag) {  // last WG of this sequence computes the output row
        const int o = tid & 31;
        const int p = tid >> 5;
        float acc = 0.f;
        const float* hb = hbar + (size_t)s * H_;
        const float* wr = Wout + (size_t)o * H_;
        for (int hh = 64 * p; hh < 64 * p + 64; ++hh) {
            float hv = __hip_atomic_load(&hb[hh], __ATOMIC_RELAXED, __HIP_MEMORY_SCOPE_AGENT);
            acc += hv * wr[hh];
        }
        red[p][o] = acc;
        __syncthreads();
        if (tid < 32) {
            float v = 0.f;
            #pragma unroll
            for (int q = 0; q < 8; ++q) v += red[q][tid];
            out[s * O_ + tid] = v * (1.f / 32.f) + bout[tid];
        }
    }
}

extern "C" void kernel_launch(void* const* d_in, const int* in_sizes, int n_in,
                              void* d_out, int out_size, void* d_ws, size_t ws_size,
                              hipStream_t stream) {
    (void)in_sizes; (void)n_in; (void)out_size; (void)ws_size;
    const float* x    = (const float*)d_in[0];
    const int*   lens = (const int*)d_in[1];
    const float* Wih  = (const float*)d_in[2];
    const float* Whh  = (const float*)d_in[3];
    const float* bih  = (const float*)d_in[4];
    const float* bhh  = (const float*)d_in[5];
    const float* Wout = (const float*)d_in[6];
    const float* bout = (const float*)d_in[7];
    float* out = (float*)d_out;

    char* wsc = (char*)d_ws;
    unsigned short* hbuf = (unsigned short*)wsc;
    float*    hbar  = (float*)(wsc + 524288);
    unsigned* flags = (unsigned*)(wsc + 540672);
    unsigned* dctr  = (unsigned*)(wsc + 542720);

    // zero h buffers + hbar + flags + done counters (graph-capture-safe)
    hipMemsetAsync(d_ws, 0, WS_NEED, stream);

    zgru_persistent<<<dim3(256), dim3(256), 0, stream>>>(
        x, lens, Wih, Whh, bih, bhh, Wout, bout, out, hbuf, hbar, flags, dctr);
}

// Round 4
// 1963.476 us; speedup vs baseline: 1.2602x; 1.2602x over previous
//
#include <hip/hip_runtime.h>
#include <hip/hip_bf16.h>

#define S_ 8
#define B_ 32
#define T_ 512
#define I_ 256
#define H_ 512
#define O_ 32

typedef __attribute__((ext_vector_type(8))) short short8;
typedef __attribute__((ext_vector_type(4))) float float4_;

__device__ inline unsigned short f2bf(float f) {
    unsigned u = __float_as_uint(f);
    u = (u + 0x7fffu + ((u >> 16) & 1u)) >> 16;   // RNE
    return (unsigned short)u;
}

__device__ inline short8 load_cvt8(const float* p) {
    float4_ a = *reinterpret_cast<const float4_*>(p);
    float4_ b = *reinterpret_cast<const float4_*>(p + 4);
    short8 r;
    r[0] = (short)f2bf(a[0]); r[1] = (short)f2bf(a[1]);
    r[2] = (short)f2bf(a[2]); r[3] = (short)f2bf(a[3]);
    r[4] = (short)f2bf(b[0]); r[5] = (short)f2bf(b[1]);
    r[6] = (short)f2bf(b[2]); r[7] = (short)f2bf(b[3]);
    return r;
}

// Agent-coherent accesses: sc0 sc1 -> coherence point (LLC). Loads valid
// only after s_waitcnt vmcnt(0).
__device__ inline short8 load_h16_coherent(const unsigned short* p) {
    short8 v;
    asm volatile("global_load_dwordx4 %0, %1, off sc0 sc1"
                 : "=v"(v) : "v"(p) : "memory");
    return v;
}
__device__ inline unsigned load_u32_coherent(const unsigned* p) {
    unsigned v;
    asm volatile("global_load_dword %0, %1, off sc0 sc1"
                 : "=v"(v) : "v"(p) : "memory");
    return v;
}
__device__ inline void store_h16_coherent(unsigned short* p, short8 v) {
    asm volatile("global_store_dwordx4 %0, %1, off sc0 sc1"
                 :: "v"(p), "v"(v) : "memory");
}
__device__ inline void store_u32_coherent(unsigned* p, unsigned v) {
    asm volatile("global_store_dword %0, %1, off sc0 sc1"
                 :: "v"(p), "v"(v) : "memory");
}
__device__ inline void wait_vm0_fence() {
    asm volatile("s_waitcnt vmcnt(0)" ::: "memory");
    __builtin_amdgcn_sched_barrier(0);
}
__device__ inline void wait_lgkm0_fence() {
    asm volatile("s_waitcnt lgkmcnt(0)" ::: "memory");
    __builtin_amdgcn_sched_barrier(0);
}

// ws layout (bytes):
//   [0, 524288)        : h bf16 double buffer [2][S][B][H]
//   [524288, 540672)   : hbar fp32 [S][H]
//   [540672, 544768)   : flags uint [S][2][64]  (per (s,m) group, 256B stride)
//   [544768, 546816)   : done counters, uint per seq, 256B stride
#define WS_NEED 546816

__global__ __launch_bounds__(256, 1)
void zgru_persistent(const float* __restrict__ x, const int* __restrict__ lens,
                     const float* __restrict__ Wih, const float* __restrict__ Whh,
                     const float* __restrict__ bih, const float* __restrict__ bhh,
                     const float* __restrict__ Wout, const float* __restrict__ bout,
                     float* __restrict__ out,
                     unsigned short* __restrict__ hbuf, float* __restrict__ hbar,
                     unsigned* __restrict__ flags, unsigned* __restrict__ done_ctr)
{
    const int tid  = threadIdx.x;
    const int wg   = blockIdx.x;
    const int s    = wg & 7;         // sequence (round-robin -> seq co-located per XCD)
    const int j    = wg >> 3;        // hidden-col group: cols [16j, 16j+16)
    const int wid  = tid >> 6;
    const int lane = tid & 63;
    const int m    = wid >> 1;       // batch half (rows 16m..16m+15)
    const int kh   = wid & 1;        // K half
    const int lrow = lane & 15;      // A-row / B-col / C-col within tile
    const int lgrp = lane >> 4;      // k-group (A/B) or row-group (C)

    const int len = lens[s];

    // ---- LDS ------------------------------------------------------------
    __shared__ unsigned short whh_lds[48 * 512];   // 48 x 1KB B-frag blocks
    __shared__ float4_ xch[2][4][64];              // [m][gate][lane] partials
    __shared__ unsigned short hsh[2][16 * 24];     // transpose staging per m
    __shared__ unsigned fxch[2];                   // kh1 -> kh0 tokens per m
    __shared__ unsigned last_flag;
    __shared__ float red[8][32];

    // ---- fill W_hh into LDS as bf16 MFMA B-fragments --------------------
    // block blk = (kh*3 + g)*8 + kc ; within block, lane ln = lgrp*16 + lc
    for (int gi = tid; gi < 48 * 64; gi += 256) {
        const int blk = gi >> 6, ln = gi & 63;
        const int khb = blk / 24, rem = blk % 24;
        const int g = rem >> 3, kc = rem & 7;
        const int lg = ln >> 4, lc = ln & 15;
        const float* src = Whh + (size_t)(g * H_ + 16 * j + lc) * H_
                         + 256 * khb + 32 * kc + 8 * lg;
        *reinterpret_cast<short8*>(&whh_lds[(size_t)blk * 512 + ln * 8]) = load_cvt8(src);
    }
    if (tid < 2) fxch[tid] = 0;

    // ---- W_ih fragments in registers (12 x 16B = 48 VGPRs) --------------
    short8 bxR[4], bxZ[4], bxN[4];
    {
        const int gr = 16 * j + lrow;
        #pragma unroll
        for (int kc = 0; kc < 4; ++kc) {
            const int k0 = 128 * kh + 32 * kc + 8 * lgrp;
            bxR[kc] = load_cvt8(Wih + (size_t)(gr          ) * I_ + k0);
            bxZ[kc] = load_cvt8(Wih + (size_t)(gr +     H_ ) * I_ + k0);
            bxN[kc] = load_cvt8(Wih + (size_t)(gr + 2 * H_ ) * I_ + k0);
        }
    }

    const int gcol   = 16 * j + lrow;
    const float bsR  = bih[gcol] + bhh[gcol];
    const float bsZ  = bih[H_ + gcol] + bhh[H_ + gcol];
    const float biN  = bih[2 * H_ + gcol];
    const float bhN_ = bhh[2 * H_ + gcol];

    __syncthreads();   // whh_lds + fxch ready (one-time)

    // ---- W_hh fragments: read once from LDS, live in registers ----------
    short8 bh[24];     // q = g*8 + kc
    #pragma unroll
    for (int q = 0; q < 24; ++q)
        bh[q] = *reinterpret_cast<const short8*>(&whh_lds[(size_t)(kh * 24 + q) * 512 + lane * 8]);

    float h[4] = {0.f, 0.f, 0.f, 0.f};

    const size_t HBUF = (size_t)S_ * B_ * H_;
    const int arow = 16 * m + lrow;
    const unsigned* fg = flags + (size_t)(s * 2 + m) * 64;   // this (s,m) group's 32 flags
    unsigned* myflag   = flags + (size_t)(s * 2 + m) * 64 + j;

    for (int t = 0; t < len; ++t) {
        // ---- recurrence-independent x part ------------------------------
        float4_ aR = {0,0,0,0}, aZ = {0,0,0,0}, aNX = {0,0,0,0};
        {
            const float* xb = x + (((size_t)s * B_ + arow) * T_ + t) * I_ + 128 * kh + 8 * lgrp;
            #pragma unroll
            for (int kc = 0; kc < 4; ++kc) {
                short8 ax = load_cvt8(xb + 32 * kc);
                aR  = __builtin_amdgcn_mfma_f32_16x16x32_bf16(ax, bxR[kc], aR, 0, 0, 0);
                aZ  = __builtin_amdgcn_mfma_f32_16x16x32_bf16(ax, bxZ[kc], aZ, 0, 0, 0);
                aNX = __builtin_amdgcn_mfma_f32_16x16x32_bf16(ax, bxN[kc], aNX, 0, 0, 0);
            }
        }

        // ---- per-(s,m) barrier: 32 producer flags must reach t ----------
        if (t > 0) {
            const unsigned tgt = (unsigned)t;
            for (;;) {
                unsigned fv = load_u32_coherent(fg + (lane & 31));
                asm volatile("s_waitcnt vmcnt(0)" ::: "memory");
                if (__ballot(fv >= tgt) == ~0ull) break;
            }
            __builtin_amdgcn_sched_barrier(0);
        }

        // ---- h A-fragments (LLC) ---------------------------------------
        const unsigned short* hr = hbuf + (size_t)(t & 1) * HBUF + (size_t)s * B_ * H_;
        short8 ah[8];
        #pragma unroll
        for (int kc = 0; kc < 8; ++kc)
            ah[kc] = load_h16_coherent(hr + (size_t)arow * H_ + 256 * kh + 32 * kc + 8 * lgrp);
        wait_vm0_fence();

        float4_ aNH = {0,0,0,0};
        #pragma unroll
        for (int kc = 0; kc < 8; ++kc) {
            aR  = __builtin_amdgcn_mfma_f32_16x16x32_bf16(ah[kc], bh[kc     ], aR,  0, 0, 0);
            aZ  = __builtin_amdgcn_mfma_f32_16x16x32_bf16(ah[kc], bh[kc +  8], aZ,  0, 0, 0);
            aNH = __builtin_amdgcn_mfma_f32_16x16x32_bf16(ah[kc], bh[kc + 16], aNH, 0, 0, 0);
        }

        if (kh == 1) {   // hand partials to kh==0 via LDS + release token
            xch[m][0][lane] = aR;
            xch[m][1][lane] = aZ;
            xch[m][2][lane] = aNH;
            xch[m][3][lane] = aNX;
            __hip_atomic_store(&fxch[m], (unsigned)(t + 1),
                               __ATOMIC_RELEASE, __HIP_MEMORY_SCOPE_WORKGROUP);
        } else {         // kh==0: merge, gates, coalesced publish, flag
            while (__hip_atomic_load(&fxch[m], __ATOMIC_ACQUIRE, __HIP_MEMORY_SCOPE_WORKGROUP)
                   < (unsigned)(t + 1)) {}
            __builtin_amdgcn_sched_barrier(0);
            aR  += xch[m][0][lane];
            aZ  += xch[m][1][lane];
            aNH += xch[m][2][lane];
            aNX += xch[m][3][lane];

            unsigned short* hs = &hsh[m][0];
            #pragma unroll
            for (int i = 0; i < 4; ++i) {
                const float pr = aR[i] + bsR;
                const float pz = aZ[i] + bsZ;
                const float r = 1.f / (1.f + __expf(-pr));
                const float z = 1.f / (1.f + __expf(-pz));
                const float pn = aNX[i] + biN + r * (aNH[i] + bhN_);
                const float e = __expf(-2.f * fabsf(pn));
                float n = (1.f - e) / (1.f + e);
                n = copysignf(n, pn);
                h[i] = z * (h[i] - n) + n;
                hs[(4 * lgrp + i) * 24 + lrow] = f2bf(h[i]);   // stage transpose
            }
            wait_lgkm0_fence();
            unsigned short* hw = hbuf + (size_t)((t + 1) & 1) * HBUF + (size_t)s * B_ * H_;
            if (lane < 32) {   // 16B/lane coalesced publish of [16 x 16] tile
                const int row = lane >> 1, cc = lane & 1;
                short8 v = *reinterpret_cast<const short8*>(&hs[row * 24 + cc * 8]);
                store_h16_coherent(hw + (size_t)(16 * m + row) * H_ + 16 * j + cc * 8, v);
            }
            asm volatile("s_waitcnt vmcnt(0)" ::: "memory");   // h at LLC
            if (lane == 0)
                store_u32_coherent(myflag, (unsigned)(t + 1));
        }
    }

    // ---- hbar[s][col] = sum_b h -----------------------------------------
    float s4 = h[0] + h[1] + h[2] + h[3];
    s4 += __shfl_xor(s4, 16);
    s4 += __shfl_xor(s4, 32);
    if (kh == 0 && lgrp == 0)
        atomicAdd(&hbar[(size_t)s * H_ + gcol], s4);   // device-scope

    __syncthreads();   // drains atomics (vmcnt 0 before barrier)
    if (tid == 0) {
        unsigned old = __hip_atomic_fetch_add(&done_ctr[s * 64], 1u,
                                              __ATOMIC_RELAXED, __HIP_MEMORY_SCOPE_AGENT);
        last_flag = (old == 31u) ? 1u : 0u;
    }
    __syncthreads();
    if (last_flag) {   // last WG of this sequence computes the output row
        const int o = tid & 31;
        const int p = tid >> 5;
        float acc = 0.f;
        const float* hb = hbar + (size_t)s * H_;
        const float* wr = Wout + (size_t)o * H_;
        for (int hh = 64 * p; hh < 64 * p + 64; ++hh) {
            float hv = __hip_atomic_load(&hb[hh], __ATOMIC_RELAXED, __HIP_MEMORY_SCOPE_AGENT);
            acc += hv * wr[hh];
        }
        red[p][o] = acc;
        __syncthreads();
        if (tid < 32) {
            float v = 0.f;
            #pragma unroll
            for (int q = 0; q < 8; ++q) v += red[q][tid];
            out[s * O_ + tid] = v * (1.f / 32.f) + bout[tid];
        }
    }
}

extern "C" void kernel_launch(void* const* d_in, const int* in_sizes, int n_in,
                              void* d_out, int out_size, void* d_ws, size_t ws_size,
                              hipStream_t stream) {
    (void)in_sizes; (void)n_in; (void)out_size; (void)ws_size;
    const float* x    = (const float*)d_in[0];
    const int*   lens = (const int*)d_in[1];
    const float* Wih  = (const float*)d_in[2];
    const float* Whh  = (const float*)d_in[3];
    const float* bih  = (const float*)d_in[4];
    const float* bhh  = (const float*)d_in[5];
    const float* Wout = (const float*)d_in[6];
    const float* bout = (const float*)d_in[7];
    float* out = (float*)d_out;

    char* wsc = (char*)d_ws;
    unsigned short* hbuf = (unsigned short*)wsc;
    float*    hbar  = (float*)(wsc + 524288);
    unsigned* flags = (unsigned*)(wsc + 540672);
    unsigned* dctr  = (unsigned*)(wsc + 544768);

    hipMemsetAsync(d_ws, 0, WS_NEED, stream);

    zgru_persistent<<<dim3(256), dim3(256), 0, stream>>>(
        x, lens, Wih, Whh, bih, bhh, Wout, bout, out, hbuf, hbar, flags, dctr);
}